// Round 1
// 2028.031 us; speedup vs baseline: 1.4049x; 1.4049x over previous
//
#include <hip/hip_runtime.h>
#include <math.h>

#define D 128
#define BM 64
#define BN 128
#define BK 32

// ---------------------------------------------------------------------------
// Generic fp32 GEMM: out[r][c] = sum_k in(r,k) * w[c][k] + bias[c]
// in(r,k): k<128 -> in0[r*128+k], else in1[r*128+k-128]  (for A2 concat input)
// Tile 64 rows x 128 cols, BK=32, 256 threads, 8x4 register blocking.
// sW transposed [BK][BN+4] -> B-fragment is a conflict-free ds_read_b128.
// ---------------------------------------------------------------------------
__global__ __launch_bounds__(256) void gemm_node(
    const float* __restrict__ in0, const float* __restrict__ in1,
    const float* __restrict__ w, const float* __restrict__ bias,
    float* __restrict__ out, int R, int din)
{
    __shared__ float sIn[BM][BK + 1];
    __shared__ alignas(16) float sW[BK][BN + 4];
    const int tid = threadIdx.x;
    const int r0 = blockIdx.x * BM;
    const int cg = tid & 31;   // col group: cols cg*4 .. cg*4+3
    const int rg = tid >> 5;   // row group: rows rg*8 .. rg*8+7

    float acc[8][4] = {};

    for (int k0 = 0; k0 < din; k0 += BK) {
        // stage input tile 64x32 (coalesced along k)
#pragma unroll
        for (int l = 0; l < 8; ++l) {
            int lin = l * 256 + tid;
            int r = lin >> 5;
            int kk = lin & 31;
            int gr = r0 + r;
            float v = 0.f;
            if (gr < R) {
                int k = k0 + kk;
                v = (k < 128) ? in0[(size_t)gr * 128 + k]
                              : in1[(size_t)gr * 128 + (k - 128)];
            }
            sIn[r][kk] = v;
        }
        // stage weight tile 128x32, transposed into sW[kk][c]
#pragma unroll
        for (int l = 0; l < 16; ++l) {
            int lin = l * 256 + tid;
            int c = lin >> 5;
            int kk = lin & 31;
            sW[kk][c] = w[(size_t)c * din + k0 + kk];
        }
        __syncthreads();
#pragma unroll
        for (int kk = 0; kk < BK; ++kk) {
            const float4 bv = *reinterpret_cast<const float4*>(&sW[kk][cg * 4]);
            float a[8];
#pragma unroll
            for (int i = 0; i < 8; ++i) a[i] = sIn[rg * 8 + i][kk];
#pragma unroll
            for (int i = 0; i < 8; ++i) {
                acc[i][0] += a[i] * bv.x;
                acc[i][1] += a[i] * bv.y;
                acc[i][2] += a[i] * bv.z;
                acc[i][3] += a[i] * bv.w;
            }
        }
        __syncthreads();
    }

    const float4 bvb = *reinterpret_cast<const float4*>(&bias[cg * 4]);
#pragma unroll
    for (int i = 0; i < 8; ++i) {
        int gr = r0 + rg * 8 + i;
        if (gr < R) {
            float4 o;
            o.x = acc[i][0] + bvb.x;
            o.y = acc[i][1] + bvb.y;
            o.z = acc[i][2] + bvb.z;
            o.w = acc[i][3] + bvb.w;
            *reinterpret_cast<float4*>(&out[(size_t)gr * 128 + cg * 4]) = o;
        }
    }
}

// ---------------------------------------------------------------------------
// Edge GEMM (B3 @ e) with fused epilogue:
//   hat_eta[r][c] = acc + B3b[c] + B1h[src[r]][c] + B2h[dst[r]][c]
// NO atomics: sigma aggregation moved to the CSR node_aggregate pass.
// ---------------------------------------------------------------------------
__global__ __launch_bounds__(256) void gemm_edge(
    const float* __restrict__ e, const float* __restrict__ w,
    const float* __restrict__ bias,
    const float* __restrict__ B1h, const float* __restrict__ B2h,
    const int* __restrict__ src, const int* __restrict__ dst,
    float* __restrict__ hat_eta, int E)
{
    __shared__ float sIn[BM][BK + 1];
    __shared__ alignas(16) float sW[BK][BN + 4];
    __shared__ int sSrc[BM];
    __shared__ int sDst[BM];
    const int tid = threadIdx.x;
    const int r0 = blockIdx.x * BM;
    const int cg = tid & 31;
    const int rg = tid >> 5;

    if (tid < BM) {
        int gr = r0 + tid;
        sSrc[tid] = (gr < E) ? src[gr] : 0;
        sDst[tid] = (gr < E) ? dst[gr] : 0;
    }

    float acc[8][4] = {};

    for (int k0 = 0; k0 < 128; k0 += BK) {
#pragma unroll
        for (int l = 0; l < 8; ++l) {
            int lin = l * 256 + tid;
            int r = lin >> 5;
            int kk = lin & 31;
            int gr = r0 + r;
            sIn[r][kk] = (gr < E) ? e[(size_t)gr * 128 + k0 + kk] : 0.f;
        }
#pragma unroll
        for (int l = 0; l < 16; ++l) {
            int lin = l * 256 + tid;
            int c = lin >> 5;
            int kk = lin & 31;
            sW[kk][c] = w[(size_t)c * 128 + k0 + kk];
        }
        __syncthreads();
#pragma unroll
        for (int kk = 0; kk < BK; ++kk) {
            const float4 bv = *reinterpret_cast<const float4*>(&sW[kk][cg * 4]);
            float a[8];
#pragma unroll
            for (int i = 0; i < 8; ++i) a[i] = sIn[rg * 8 + i][kk];
#pragma unroll
            for (int i = 0; i < 8; ++i) {
                acc[i][0] += a[i] * bv.x;
                acc[i][1] += a[i] * bv.y;
                acc[i][2] += a[i] * bv.z;
                acc[i][3] += a[i] * bv.w;
            }
        }
        __syncthreads();
    }

    const float4 bvb = *reinterpret_cast<const float4*>(&bias[cg * 4]);
#pragma unroll
    for (int i = 0; i < 8; ++i) {
        int r = rg * 8 + i;
        int gr = r0 + r;
        if (gr < E) {
            const int sn = sSrc[r];
            const int dn = sDst[r];
            const float4 b1 = *reinterpret_cast<const float4*>(&B1h[(size_t)sn * 128 + cg * 4]);
            const float4 b2 = *reinterpret_cast<const float4*>(&B2h[(size_t)dn * 128 + cg * 4]);
            float4 o;
            o.x = acc[i][0] + bvb.x + b1.x + b2.x;
            o.y = acc[i][1] + bvb.y + b1.y + b2.y;
            o.z = acc[i][2] + bvb.z + b1.z + b2.z;
            o.w = acc[i][3] + bvb.w + b1.w + b2.w;
            *reinterpret_cast<float4*>(&hat_eta[(size_t)gr * 128 + cg * 4]) = o;
        }
    }
}

// ---------------------------------------------------------------------------
// CSR build over dst: count, single-block scan, scatter.
// ---------------------------------------------------------------------------
__global__ __launch_bounds__(256) void csr_count(
    const int* __restrict__ dst, int* __restrict__ cnt, int E_)
{
    int e = blockIdx.x * 256 + threadIdx.x;
    if (e < E_) atomicAdd(&cnt[dst[e]], 1);
}

__global__ __launch_bounds__(1024) void csr_scan(
    int* __restrict__ cursor, int* __restrict__ ioff, int n)
{
    __shared__ int tmp[1024];
    __shared__ int carry;
    const int tid = threadIdx.x;
    if (tid == 0) carry = 0;
    __syncthreads();
    for (int base = 0; base < n; base += 1024) {
        int i = base + tid;
        int v = (i < n) ? cursor[i] : 0;
        int x = v;
        tmp[tid] = x;
        __syncthreads();
        for (int s = 1; s < 1024; s <<= 1) {
            int y = (tid >= s) ? tmp[tid - s] : 0;
            __syncthreads();
            x += y;
            tmp[tid] = x;
            __syncthreads();
        }
        int excl = x - v + carry;            // reads carry BEFORE update
        if (i < n) { ioff[i] = excl; cursor[i] = excl; }
        int total = tmp[1023];
        __syncthreads();
        if (tid == 0) carry += total;
        __syncthreads();
    }
    if (tid == 0) ioff[n] = carry;
}

__global__ __launch_bounds__(256) void csr_scatter(
    const int* __restrict__ dst, int* __restrict__ cursor,
    int* __restrict__ eids, int E_)
{
    int e = blockIdx.x * 256 + threadIdx.x;
    if (e < E_) {
        int p = atomicAdd(&cursor[dst[e]], 1);
        eids[p] = e;
    }
}

// ---------------------------------------------------------------------------
// Per-dst-node aggregation, zero float atomics:
//   ss   = sum sigma_j           (j over incoming edges)
//   hacc = sum sigma_j * A2hp[src_j] ; pacc = sum sigma_j * C2p[src_j]
//   h_new[n] += hacc/(ss+eps)  (h_new holds A1h on entry; final pre-BN value)
//   out_p[n]  = p[n] + tanh(C1p[n] + pacc/(ss+eps))   (finalize_p fused)
// Fused column stats: e-BN stats from hat_eta stream, h-BN stats from h_new.
// ---------------------------------------------------------------------------
__global__ __launch_bounds__(256) void node_aggregate(
    const float* __restrict__ hat_eta,
    const int* __restrict__ ioff, const int* __restrict__ eids,
    const int* __restrict__ src,
    const float* __restrict__ A2hp, const float* __restrict__ C2p,
    float* __restrict__ h_new, const float* __restrict__ C1p,
    const float* __restrict__ p, float* __restrict__ out_p,
    float* __restrict__ h_stats, float* __restrict__ e_stats, int Nn)
{
    const int tid = threadIdx.x;
    const int d = tid & 127;
    const int half = tid >> 7;
    float e1 = 0.f, e2 = 0.f, hs1 = 0.f, hs2 = 0.f;
    for (int n = blockIdx.x * 2 + half; n < Nn; n += gridDim.x * 2) {
        const int beg = ioff[n];
        const int end = ioff[n + 1];
        float ss = 0.f, hacc = 0.f, pacc = 0.f;
        for (int t = beg; t < end; ++t) {
            const int ed = eids[t];
            const int sn = src[ed];
            const float he = hat_eta[(size_t)ed * 128 + d];
            e1 += he;
            e2 += he * he;
            const float sg = 1.f / (1.f + expf(-he));
            ss += sg;
            hacc += sg * A2hp[(size_t)sn * 128 + d];
            pacc += sg * C2p[(size_t)sn * 128 + d];
        }
        const float inv = 1.f / (ss + 1e-6f);
        const size_t idx = (size_t)n * 128 + d;
        const float hv = h_new[idx] + hacc * inv;
        h_new[idx] = hv;
        hs1 += hv;
        hs2 += hv * hv;
        out_p[idx] = p[idx] + tanhf(C1p[idx] + pacc * inv);
    }
    __shared__ float red[256];
    red[tid] = e1; __syncthreads();
    if (tid < 128) atomicAdd(&e_stats[d], red[tid] + red[tid + 128]);
    __syncthreads(); red[tid] = e2; __syncthreads();
    if (tid < 128) atomicAdd(&e_stats[128 + d], red[tid] + red[tid + 128]);
    __syncthreads(); red[tid] = hs1; __syncthreads();
    if (tid < 128) atomicAdd(&h_stats[d], red[tid] + red[tid + 128]);
    __syncthreads(); red[tid] = hs2; __syncthreads();
    if (tid < 128) atomicAdd(&h_stats[128 + d], red[tid] + red[tid + 128]);
}

// ---------------------------------------------------------------------------
// out = resid + relu( g*(x-m)*rsqrt(v+eps) + b ), stats-driven BN (biased var)
// ---------------------------------------------------------------------------
__global__ __launch_bounds__(256) void finalize_bn_relu_res(
    const float* __restrict__ resid, const float* __restrict__ xnew,
    const float* __restrict__ stats, const float* __restrict__ g,
    const float* __restrict__ bb, float* __restrict__ out,
    size_t total, float invR)
{
    size_t idx = (size_t)blockIdx.x * 256 + threadIdx.x;
    if (idx >= total) return;
    int d = (int)(idx & 127);
    float m = stats[d] * invR;
    float var = stats[128 + d] * invR - m * m;
    if (var < 0.f) var = 0.f;
    float x = xnew[idx];
    float y = g[d] * (x - m) * rsqrtf(var + 1e-5f) + bb[d];
    y = y > 0.f ? y : 0.f;
    out[idx] = resid[idx] + y;
}

// ---------------------------------------------------------------------------
extern "C" void kernel_launch(void* const* d_in, const int* in_sizes, int n_in,
                              void* d_out, int out_size, void* d_ws, size_t ws_size,
                              hipStream_t stream)
{
    const float* h   = (const float*)d_in[0];
    const float* e   = (const float*)d_in[1];
    const float* p   = (const float*)d_in[2];
    const int* src   = (const int*)d_in[3];
    const int* dst   = (const int*)d_in[4];
    const float* A1w = (const float*)d_in[5];
    const float* A1b = (const float*)d_in[6];
    const float* A2w = (const float*)d_in[7];
    const float* A2b = (const float*)d_in[8];
    const float* B1w = (const float*)d_in[9];
    const float* B1b = (const float*)d_in[10];
    const float* B2w = (const float*)d_in[11];
    const float* B2b = (const float*)d_in[12];
    const float* B3w = (const float*)d_in[13];
    const float* B3b = (const float*)d_in[14];
    const float* C1w = (const float*)d_in[15];
    const float* C1b = (const float*)d_in[16];
    const float* C2w = (const float*)d_in[17];
    const float* C2b = (const float*)d_in[18];
    const float* bn_h_g = (const float*)d_in[19];
    const float* bn_h_b = (const float*)d_in[20];
    const float* bn_e_g = (const float*)d_in[21];
    const float* bn_e_b = (const float*)d_in[22];

    const int N = in_sizes[0] / D;   // 50000
    const int E = in_sizes[3];       // 600000
    const size_t ND = (size_t)N * D;
    const size_t ED = (size_t)E * D;

    float* out_h = (float*)d_out;
    float* out_e = out_h + ND;       // hat_eta lives here until finalize (e)
    float* out_p = out_e + ED;

    float* ws = (float*)d_ws;
    float* B1h    = ws;
    float* B2h    = B1h + ND;
    float* A2hp   = B2h + ND;
    float* C2p    = A2hp + ND;
    float* h_new  = C2p + ND;
    float* C1p    = h_new + ND;
    float* stats  = C1p + ND;            // h_stats [0,256) | e_stats [256,512)
    int*   ioff   = (int*)(stats + 512); // N+1
    int*   cursor = ioff + (N + 1);      // N  (deg during count, then cursors)
    int*   eids   = cursor + N;          // E

    // zero: stats (512 f) + ioff (N+1) + cursor (N)  — contiguous
    hipMemsetAsync(stats, 0,
                   512 * sizeof(float) + (size_t)(2 * N + 1) * sizeof(int),
                   stream);

    const int gN = (N + BM - 1) / BM;
    const int gE = (E + BM - 1) / BM;
    const int gEt = (E + 255) / 256;

    // CSR degree count (only needs dst; overlaps nothing but cheap)
    csr_count<<<gEt, 256, 0, stream>>>(dst, cursor, E);

    // node linears
    gemm_node<<<gN, 256, 0, stream>>>(h, nullptr, A1w, A1b, h_new, N, 128);
    gemm_node<<<gN, 256, 0, stream>>>(h, nullptr, B1w, B1b, B1h, N, 128);
    gemm_node<<<gN, 256, 0, stream>>>(h, nullptr, B2w, B2b, B2h, N, 128);
    gemm_node<<<gN, 256, 0, stream>>>(p, nullptr, C1w, C1b, C1p, N, 128);
    gemm_node<<<gN, 256, 0, stream>>>(p, nullptr, C2w, C2b, C2p, N, 128);
    gemm_node<<<gN, 256, 0, stream>>>(h, p, A2w, A2b, A2hp, N, 256);

    // finish CSR
    csr_scan<<<1, 1024, 0, stream>>>(cursor, ioff, N);
    csr_scatter<<<gEt, 256, 0, stream>>>(dst, cursor, eids, E);

    // edge linear -> hat_eta (no atomics)
    gemm_edge<<<gE, 256, 0, stream>>>(e, B3w, B3b, B1h, B2h, src, dst,
                                      out_e, E);

    // per-node aggregation + p finalize + both BN stats, zero float atomics
    node_aggregate<<<2048, 256, 0, stream>>>(out_e, ioff, eids, src,
                                             A2hp, C2p, h_new, C1p, p, out_p,
                                             stats, stats + 256, N);

    // finalizers (h over ND, e over ED)
    {
        int blocks = (int)((ND + 255) / 256);
        finalize_bn_relu_res<<<blocks, 256, 0, stream>>>(
            h, h_new, stats, bn_h_g, bn_h_b, out_h, ND, 1.f / (float)N);
    }
    {
        int blocks = (int)((ED + 255) / 256);
        finalize_bn_relu_res<<<blocks, 256, 0, stream>>>(
            e, out_e, stats + 256, bn_e_g, bn_e_b, out_e, ED, 1.f / (float)E);
    }
}

// Round 2
// 1773.023 us; speedup vs baseline: 1.6069x; 1.1438x over previous
//
#include <hip/hip_runtime.h>
#include <math.h>

#define D 128
#define BM 256
#define BN 128
#define BK 32

// ---------------------------------------------------------------------------
// fp32 GEMM, LDS-instruction-minimized:
//   out[r][c] = sum_k in(r,k) * w[c][k] + bias[c]
//   in(r,k): k<128 -> in0[r*128+k], else in1[r*128+k-128]  (A2 concat input)
// Tile 256x128, BK=32, 256 threads, 16x8 register blocking.
// sIn staged TRANSPOSED [BK][BM+4]; sW [BK][BN+4]. Both with XOR swizzle
// (col ^= (kk>>2)<<2) so the transposed b32 stores are bank-spread while
// inner-loop reads stay single-b128 per fragment.
// Inner loop per kk: 4+2 ds_read_b128 for 128 FMAs.
// ---------------------------------------------------------------------------
__global__ __launch_bounds__(256) void gemm_node(
    const float* __restrict__ in0, const float* __restrict__ in1,
    const float* __restrict__ w, const float* __restrict__ bias,
    float* __restrict__ out, int R, int din)
{
    __shared__ float sIn[BK][BM + 4];
    __shared__ float sW[BK][BN + 4];
    const int tid = threadIdx.x;
    const int r0 = blockIdx.x * BM;
    const int cg = tid & 15;        // cols cg*8 .. cg*8+7
    const int rg = tid >> 4;        // rows rg*16 .. rg*16+15
    const int s_kk4 = tid & 7;      // staging: float4 index along k
    const int s_r   = tid >> 3;     // staging: row (+32 per iter)

    float acc[16][8] = {};

    for (int k0 = 0; k0 < din; k0 += BK) {
        // stage input 256x32, transposed, float4 global loads
#pragma unroll
        for (int l = 0; l < 8; ++l) {
            int r = s_r + l * 32;
            int gr = r0 + r;
            float4 v = {0.f, 0.f, 0.f, 0.f};
            if (gr < R) {
                int k = k0 + s_kk4 * 4;
                const float* base = (k < 128)
                    ? &in0[(size_t)gr * 128 + k]
                    : &in1[(size_t)gr * 128 + (k - 128)];
                v = *reinterpret_cast<const float4*>(base);
            }
            int col = r ^ (s_kk4 << 2);
            sIn[s_kk4 * 4 + 0][col] = v.x;
            sIn[s_kk4 * 4 + 1][col] = v.y;
            sIn[s_kk4 * 4 + 2][col] = v.z;
            sIn[s_kk4 * 4 + 3][col] = v.w;
        }
        // stage weights 128x32, transposed
#pragma unroll
        for (int l = 0; l < 4; ++l) {
            int c = s_r + l * 32;
            float4 v = *reinterpret_cast<const float4*>(
                &w[(size_t)c * din + k0 + s_kk4 * 4]);
            int col = c ^ (s_kk4 << 2);
            sW[s_kk4 * 4 + 0][col] = v.x;
            sW[s_kk4 * 4 + 1][col] = v.y;
            sW[s_kk4 * 4 + 2][col] = v.z;
            sW[s_kk4 * 4 + 3][col] = v.w;
        }
        __syncthreads();
#pragma unroll 4
        for (int kk = 0; kk < BK; ++kk) {
            const int X = (kk >> 2) << 2;
            float a[16], b[8];
#pragma unroll
            for (int q = 0; q < 4; ++q) {
                float4 t = *reinterpret_cast<const float4*>(
                    &sIn[kk][(rg * 16 + q * 4) ^ X]);
                a[q * 4 + 0] = t.x; a[q * 4 + 1] = t.y;
                a[q * 4 + 2] = t.z; a[q * 4 + 3] = t.w;
            }
#pragma unroll
            for (int q = 0; q < 2; ++q) {
                float4 t = *reinterpret_cast<const float4*>(
                    &sW[kk][(cg * 8 + q * 4) ^ X]);
                b[q * 4 + 0] = t.x; b[q * 4 + 1] = t.y;
                b[q * 4 + 2] = t.z; b[q * 4 + 3] = t.w;
            }
#pragma unroll
            for (int i = 0; i < 16; ++i)
#pragma unroll
                for (int j = 0; j < 8; ++j)
                    acc[i][j] += a[i] * b[j];
        }
        __syncthreads();
    }

    const float4 bv0 = *reinterpret_cast<const float4*>(&bias[cg * 8]);
    const float4 bv1 = *reinterpret_cast<const float4*>(&bias[cg * 8 + 4]);
#pragma unroll
    for (int i = 0; i < 16; ++i) {
        int gr = r0 + rg * 16 + i;
        if (gr < R) {
            float4 o0, o1;
            o0.x = acc[i][0] + bv0.x; o0.y = acc[i][1] + bv0.y;
            o0.z = acc[i][2] + bv0.z; o0.w = acc[i][3] + bv0.w;
            o1.x = acc[i][4] + bv1.x; o1.y = acc[i][5] + bv1.y;
            o1.z = acc[i][6] + bv1.z; o1.w = acc[i][7] + bv1.w;
            float* op = &out[(size_t)gr * 128 + cg * 8];
            *reinterpret_cast<float4*>(op) = o0;
            *reinterpret_cast<float4*>(op + 4) = o1;
        }
    }
}

// ---------------------------------------------------------------------------
// Edge GEMM (B3 @ e), same tiling, fused epilogue:
//   hat_eta[r][c] = acc + B3b[c] + B1h[src[r]][c] + B2h[dst[r]][c]
// ---------------------------------------------------------------------------
__global__ __launch_bounds__(256) void gemm_edge(
    const float* __restrict__ e, const float* __restrict__ w,
    const float* __restrict__ bias,
    const float* __restrict__ B1h, const float* __restrict__ B2h,
    const int* __restrict__ src, const int* __restrict__ dst,
    float* __restrict__ hat_eta, int E)
{
    __shared__ float sIn[BK][BM + 4];
    __shared__ float sW[BK][BN + 4];
    __shared__ int sSrc[BM];
    __shared__ int sDst[BM];
    const int tid = threadIdx.x;
    const int r0 = blockIdx.x * BM;
    const int cg = tid & 15;
    const int rg = tid >> 4;
    const int s_kk4 = tid & 7;
    const int s_r   = tid >> 3;

    {
        int gr = r0 + tid;
        sSrc[tid] = (gr < E) ? src[gr] : 0;
        sDst[tid] = (gr < E) ? dst[gr] : 0;
    }

    float acc[16][8] = {};

    for (int k0 = 0; k0 < 128; k0 += BK) {
#pragma unroll
        for (int l = 0; l < 8; ++l) {
            int r = s_r + l * 32;
            int gr = r0 + r;
            float4 v = {0.f, 0.f, 0.f, 0.f};
            if (gr < E)
                v = *reinterpret_cast<const float4*>(
                    &e[(size_t)gr * 128 + k0 + s_kk4 * 4]);
            int col = r ^ (s_kk4 << 2);
            sIn[s_kk4 * 4 + 0][col] = v.x;
            sIn[s_kk4 * 4 + 1][col] = v.y;
            sIn[s_kk4 * 4 + 2][col] = v.z;
            sIn[s_kk4 * 4 + 3][col] = v.w;
        }
#pragma unroll
        for (int l = 0; l < 4; ++l) {
            int c = s_r + l * 32;
            float4 v = *reinterpret_cast<const float4*>(
                &w[(size_t)c * 128 + k0 + s_kk4 * 4]);
            int col = c ^ (s_kk4 << 2);
            sW[s_kk4 * 4 + 0][col] = v.x;
            sW[s_kk4 * 4 + 1][col] = v.y;
            sW[s_kk4 * 4 + 2][col] = v.z;
            sW[s_kk4 * 4 + 3][col] = v.w;
        }
        __syncthreads();
#pragma unroll 4
        for (int kk = 0; kk < BK; ++kk) {
            const int X = (kk >> 2) << 2;
            float a[16], b[8];
#pragma unroll
            for (int q = 0; q < 4; ++q) {
                float4 t = *reinterpret_cast<const float4*>(
                    &sIn[kk][(rg * 16 + q * 4) ^ X]);
                a[q * 4 + 0] = t.x; a[q * 4 + 1] = t.y;
                a[q * 4 + 2] = t.z; a[q * 4 + 3] = t.w;
            }
#pragma unroll
            for (int q = 0; q < 2; ++q) {
                float4 t = *reinterpret_cast<const float4*>(
                    &sW[kk][(cg * 8 + q * 4) ^ X]);
                b[q * 4 + 0] = t.x; b[q * 4 + 1] = t.y;
                b[q * 4 + 2] = t.z; b[q * 4 + 3] = t.w;
            }
#pragma unroll
            for (int i = 0; i < 16; ++i)
#pragma unroll
                for (int j = 0; j < 8; ++j)
                    acc[i][j] += a[i] * b[j];
        }
        __syncthreads();
    }

    const float4 bv0 = *reinterpret_cast<const float4*>(&bias[cg * 8]);
    const float4 bv1 = *reinterpret_cast<const float4*>(&bias[cg * 8 + 4]);
#pragma unroll
    for (int i = 0; i < 16; ++i) {
        int r = rg * 16 + i;
        int gr = r0 + r;
        if (gr < E) {
            const int sn = sSrc[r];
            const int dn = sDst[r];
            const float* p1 = &B1h[(size_t)sn * 128 + cg * 8];
            const float* p2 = &B2h[(size_t)dn * 128 + cg * 8];
            const float4 a1 = *reinterpret_cast<const float4*>(p1);
            const float4 a2 = *reinterpret_cast<const float4*>(p1 + 4);
            const float4 c1 = *reinterpret_cast<const float4*>(p2);
            const float4 c2 = *reinterpret_cast<const float4*>(p2 + 4);
            float4 o0, o1;
            o0.x = acc[i][0] + bv0.x + a1.x + c1.x;
            o0.y = acc[i][1] + bv0.y + a1.y + c1.y;
            o0.z = acc[i][2] + bv0.z + a1.z + c1.z;
            o0.w = acc[i][3] + bv0.w + a1.w + c1.w;
            o1.x = acc[i][4] + bv1.x + a2.x + c2.x;
            o1.y = acc[i][5] + bv1.y + a2.y + c2.y;
            o1.z = acc[i][6] + bv1.z + a2.z + c2.z;
            o1.w = acc[i][7] + bv1.w + a2.w + c2.w;
            float* op = &hat_eta[(size_t)gr * 128 + cg * 8];
            *reinterpret_cast<float4*>(op) = o0;
            *reinterpret_cast<float4*>(op + 4) = o1;
        }
    }
}

// ---------------------------------------------------------------------------
// CSR build over dst: count, single-block scan, scatter.
// ---------------------------------------------------------------------------
__global__ __launch_bounds__(256) void csr_count(
    const int* __restrict__ dst, int* __restrict__ cnt, int E_)
{
    int e = blockIdx.x * 256 + threadIdx.x;
    if (e < E_) atomicAdd(&cnt[dst[e]], 1);
}

__global__ __launch_bounds__(1024) void csr_scan(
    int* __restrict__ cursor, int* __restrict__ ioff, int n)
{
    __shared__ int tmp[1024];
    __shared__ int carry;
    const int tid = threadIdx.x;
    if (tid == 0) carry = 0;
    __syncthreads();
    for (int base = 0; base < n; base += 1024) {
        int i = base + tid;
        int v = (i < n) ? cursor[i] : 0;
        int x = v;
        tmp[tid] = x;
        __syncthreads();
        for (int s = 1; s < 1024; s <<= 1) {
            int y = (tid >= s) ? tmp[tid - s] : 0;
            __syncthreads();
            x += y;
            tmp[tid] = x;
            __syncthreads();
        }
        int excl = x - v + carry;
        if (i < n) { ioff[i] = excl; cursor[i] = excl; }
        int total = tmp[1023];
        __syncthreads();
        if (tid == 0) carry += total;
        __syncthreads();
    }
    if (tid == 0) ioff[n] = carry;
}

__global__ __launch_bounds__(256) void csr_scatter(
    const int* __restrict__ dst, int* __restrict__ cursor,
    int* __restrict__ eids, int E_)
{
    int e = blockIdx.x * 256 + threadIdx.x;
    if (e < E_) {
        int p = atomicAdd(&cursor[dst[e]], 1);
        eids[p] = e;
    }
}

// ---------------------------------------------------------------------------
// Per-dst-node aggregation, zero float atomics:
//   ss = sum sigma ; hacc = sum sigma*A2hp[src] ; pacc = sum sigma*C2p[src]
//   h_new[n] += hacc/(ss+eps) ; out_p[n] = p[n] + tanh(C1p[n] + pacc/(ss+eps))
// Fused BN column stats for e (from hat_eta stream) and h (from h_new).
// ---------------------------------------------------------------------------
__global__ __launch_bounds__(256) void node_aggregate(
    const float* __restrict__ hat_eta,
    const int* __restrict__ ioff, const int* __restrict__ eids,
    const int* __restrict__ src,
    const float* __restrict__ A2hp, const float* __restrict__ C2p,
    float* __restrict__ h_new, const float* __restrict__ C1p,
    const float* __restrict__ p, float* __restrict__ out_p,
    float* __restrict__ h_stats, float* __restrict__ e_stats, int Nn)
{
    const int tid = threadIdx.x;
    const int d = tid & 127;
    const int half = tid >> 7;
    float e1 = 0.f, e2 = 0.f, hs1 = 0.f, hs2 = 0.f;
    for (int n = blockIdx.x * 2 + half; n < Nn; n += gridDim.x * 2) {
        const int beg = ioff[n];
        const int end = ioff[n + 1];
        float ss = 0.f, hacc = 0.f, pacc = 0.f;
        for (int t = beg; t < end; ++t) {
            const int ed = eids[t];
            const int sn = src[ed];
            const float he = hat_eta[(size_t)ed * 128 + d];
            e1 += he;
            e2 += he * he;
            const float sg = 1.f / (1.f + expf(-he));
            ss += sg;
            hacc += sg * A2hp[(size_t)sn * 128 + d];
            pacc += sg * C2p[(size_t)sn * 128 + d];
        }
        const float inv = 1.f / (ss + 1e-6f);
        const size_t idx = (size_t)n * 128 + d;
        const float hv = h_new[idx] + hacc * inv;
        h_new[idx] = hv;
        hs1 += hv;
        hs2 += hv * hv;
        out_p[idx] = p[idx] + tanhf(C1p[idx] + pacc * inv);
    }
    __shared__ float red[256];
    red[tid] = e1; __syncthreads();
    if (tid < 128) atomicAdd(&e_stats[d], red[tid] + red[tid + 128]);
    __syncthreads(); red[tid] = e2; __syncthreads();
    if (tid < 128) atomicAdd(&e_stats[128 + d], red[tid] + red[tid + 128]);
    __syncthreads(); red[tid] = hs1; __syncthreads();
    if (tid < 128) atomicAdd(&h_stats[d], red[tid] + red[tid + 128]);
    __syncthreads(); red[tid] = hs2; __syncthreads();
    if (tid < 128) atomicAdd(&h_stats[128 + d], red[tid] + red[tid + 128]);
}

// ---------------------------------------------------------------------------
// out = resid + relu( g*(x-m)*rsqrt(v+eps) + b ), stats-driven BN (biased var)
// ---------------------------------------------------------------------------
__global__ __launch_bounds__(256) void finalize_bn_relu_res(
    const float* __restrict__ resid, const float* __restrict__ xnew,
    const float* __restrict__ stats, const float* __restrict__ g,
    const float* __restrict__ bb, float* __restrict__ out,
    size_t total, float invR)
{
    size_t idx = (size_t)blockIdx.x * 256 + threadIdx.x;
    if (idx >= total) return;
    int d = (int)(idx & 127);
    float m = stats[d] * invR;
    float var = stats[128 + d] * invR - m * m;
    if (var < 0.f) var = 0.f;
    float x = xnew[idx];
    float y = g[d] * (x - m) * rsqrtf(var + 1e-5f) + bb[d];
    y = y > 0.f ? y : 0.f;
    out[idx] = resid[idx] + y;
}

// ---------------------------------------------------------------------------
extern "C" void kernel_launch(void* const* d_in, const int* in_sizes, int n_in,
                              void* d_out, int out_size, void* d_ws, size_t ws_size,
                              hipStream_t stream)
{
    const float* h   = (const float*)d_in[0];
    const float* e   = (const float*)d_in[1];
    const float* p   = (const float*)d_in[2];
    const int* src   = (const int*)d_in[3];
    const int* dst   = (const int*)d_in[4];
    const float* A1w = (const float*)d_in[5];
    const float* A1b = (const float*)d_in[6];
    const float* A2w = (const float*)d_in[7];
    const float* A2b = (const float*)d_in[8];
    const float* B1w = (const float*)d_in[9];
    const float* B1b = (const float*)d_in[10];
    const float* B2w = (const float*)d_in[11];
    const float* B2b = (const float*)d_in[12];
    const float* B3w = (const float*)d_in[13];
    const float* B3b = (const float*)d_in[14];
    const float* C1w = (const float*)d_in[15];
    const float* C1b = (const float*)d_in[16];
    const float* C2w = (const float*)d_in[17];
    const float* C2b = (const float*)d_in[18];
    const float* bn_h_g = (const float*)d_in[19];
    const float* bn_h_b = (const float*)d_in[20];
    const float* bn_e_g = (const float*)d_in[21];
    const float* bn_e_b = (const float*)d_in[22];

    const int N = in_sizes[0] / D;   // 50000
    const int E = in_sizes[3];       // 600000
    const size_t ND = (size_t)N * D;
    const size_t ED = (size_t)E * D;

    float* out_h = (float*)d_out;
    float* out_e = out_h + ND;       // hat_eta lives here until finalize (e)
    float* out_p = out_e + ED;

    float* ws = (float*)d_ws;
    float* B1h    = ws;
    float* B2h    = B1h + ND;
    float* A2hp   = B2h + ND;
    float* C2p    = A2hp + ND;
    float* h_new  = C2p + ND;
    float* C1p    = h_new + ND;
    float* stats  = C1p + ND;            // h_stats [0,256) | e_stats [256,512)
    int*   ioff   = (int*)(stats + 512); // N+1
    int*   cursor = ioff + (N + 1);      // N
    int*   eids   = cursor + N;          // E

    hipMemsetAsync(stats, 0,
                   512 * sizeof(float) + (size_t)(2 * N + 1) * sizeof(int),
                   stream);

    const int gN = (N + BM - 1) / BM;
    const int gE = (E + BM - 1) / BM;
    const int gEt = (E + 255) / 256;

    csr_count<<<gEt, 256, 0, stream>>>(dst, cursor, E);

    // node linears
    gemm_node<<<gN, 256, 0, stream>>>(h, nullptr, A1w, A1b, h_new, N, 128);
    gemm_node<<<gN, 256, 0, stream>>>(h, nullptr, B1w, B1b, B1h, N, 128);
    gemm_node<<<gN, 256, 0, stream>>>(h, nullptr, B2w, B2b, B2h, N, 128);
    gemm_node<<<gN, 256, 0, stream>>>(p, nullptr, C1w, C1b, C1p, N, 128);
    gemm_node<<<gN, 256, 0, stream>>>(p, nullptr, C2w, C2b, C2p, N, 128);
    gemm_node<<<gN, 256, 0, stream>>>(h, p, A2w, A2b, A2hp, N, 256);

    csr_scan<<<1, 1024, 0, stream>>>(cursor, ioff, N);
    csr_scatter<<<gEt, 256, 0, stream>>>(dst, cursor, eids, E);

    gemm_edge<<<gE, 256, 0, stream>>>(e, B3w, B3b, B1h, B2h, src, dst,
                                      out_e, E);

    node_aggregate<<<2048, 256, 0, stream>>>(out_e, ioff, eids, src,
                                             A2hp, C2p, h_new, C1p, p, out_p,
                                             stats, stats + 256, N);

    {
        int blocks = (int)((ND + 255) / 256);
        finalize_bn_relu_res<<<blocks, 256, 0, stream>>>(
            h, h_new, stats, bn_h_g, bn_h_b, out_h, ND, 1.f / (float)N);
    }
    {
        int blocks = (int)((ED + 255) / 256);
        finalize_bn_relu_res<<<blocks, 256, 0, stream>>>(
            e, out_e, stats + 256, bn_e_g, bn_e_b, out_e, ED, 1.f / (float)E);
    }
}